// Round 9
// baseline (35.031 us; speedup 1.0000x reference)
//
#include <hip/hip_runtime.h>
#include <hip/hip_bf16.h>

// DecoderBlock: block-sparse masked linear (8 GEMMs M=256,N=1024,K=1024)
// + BatchNorm1d (batch stats; bias cancels exactly) + Swish.
// SINGLE DISPATCH, no workspace, no inter-block dependencies:
// block = full batch (256 rows) x 32 features -> BN stats block-local.
// grid 256 = 8 g x 32 nt; g = bid&7 -> XCD-local x g-slice (L2-resident f32).
// A (x) read as f32 via global_load_lds (src XOR-preswizzled), converted to
// bf16 in-register at fragment time; W f32 reg-ring depth 2 -> bf16 -> LDS.
// K-loop: BK=32, 32 steps, r4-proven schedule with counted vmcnt(9).

typedef float  f32x4  __attribute__((ext_vector_type(4)));
typedef short  short8 __attribute__((ext_vector_type(8)));
typedef unsigned int u32x2 __attribute__((ext_vector_type(2)));

static __device__ __forceinline__ unsigned int f2bf(float f) {
    unsigned int u = __float_as_uint(f);
    u += 0x7FFFu + ((u >> 16) & 1u);          // RNE (inputs finite)
    return u >> 16;                            // low 16 bits valid
}

#define GLL(gp, lp) __builtin_amdgcn_global_load_lds( \
    (const __attribute__((address_space(1))) unsigned int*)(gp), \
    (__attribute__((address_space(3))) unsigned int*)(lp), 16, 0, 0)

__global__ __launch_bounds__(256, 1) void fused_kernel(
    const float* __restrict__ x, const float* __restrict__ W,
    const float* __restrict__ gamma, const float* __restrict__ beta,
    float* __restrict__ out)
{
    __shared__ __align__(16) char ldsA[3][32768];   // [256 rows][32 f32], swizzled
    __shared__ __align__(16) char ldsB[2][2048];    // [32 n][32 k] bf16, swizzled
    __shared__ float wps1[4][32], wps2[4][32];
    __shared__ float sa[32], sb[32];

    const int bid = blockIdx.x;
    const int g   = bid & 7;               // channel group -> XCD (round-robin)
    const int nt  = bid >> 3;              // 0..31
    const int o   = g * 4 + (nt >> 3);
    const int f0  = (nt & 7) * 32;
    const int gcol0 = o * 256 + f0;

    const int t    = threadIdx.x;
    const int wave = t >> 6;
    const int lane = t & 63;
    const int lr   = lane & 15;
    const int kq   = lane >> 4;

    f32x4 acc[4][2];
    const f32x4 zero = {0.f, 0.f, 0.f, 0.f};
#pragma unroll
    for (int i = 0; i < 4; ++i) { acc[i][0] = zero; acc[i][1] = zero; }

    f32x4 breg[2];                          // W ring, depth 2 (16B/thread/step)

    auto ISSUE = [&](int st) {              // 1 W-load + 8 GLL = 9 vm ops
        const float* bsrc = W + ((size_t)((o * 32 + g * 4 + (st >> 3)) * 256 + f0)) * 256
                              + (st & 7) * 32 + (size_t)(t >> 3) * 256 + (t & 7) * 4;
        breg[st & 1] = *(const f32x4*)bsrc;
        const float* asrc = x + g * 1024 + st * 32;
        char* Ab = ldsA[st % 3];
#pragma unroll
        for (int i = 0; i < 8; ++i) {
            const int cid = i * 256 + t;            // 16B-chunk id, 0..2047
            const int r = cid >> 3, c = cid & 7;    // row, chunk-in-row (8x16B = 128B row)
            GLL(asrc + (size_t)r * 8192 + (size_t)((c ^ (r & 7)) * 4), Ab + cid * 16);
        }
    };
    auto WRITEB = [&](int st) {             // cvt 4 f32 -> bf16, swizzled 8B write
        const int n = t >> 3;               // feature row 0..31
        const int c2 = (t & 7) >> 1;        // 16B chunk 0..3 within 64B row
        const int slot = c2 ^ ((n >> 1) & 3);
        const f32x4 v = breg[st & 1];
        u32x2 d;
        d[0] = f2bf(v[0]) | (f2bf(v[1]) << 16);
        d[1] = f2bf(v[2]) | (f2bf(v[3]) << 16);
        *(u32x2*)(ldsB[st & 1] + n * 64 + slot * 16 + (t & 1) * 8) = d;
    };
    auto COMPUTE = [&](int st) {
        const char* Ab = ldsA[st % 3];
        const char* Bb = ldsB[st & 1];
        short8 af[4], bfr[2];
#pragma unroll
        for (int i = 0; i < 4; ++i) {
            const int ra = wave * 64 + i * 16 + lr;
            const int s = ra & 7;
            const f32x4 lo = *(const f32x4*)(Ab + ra * 128 + (((kq * 2) ^ s) * 16));
            const f32x4 hi = *(const f32x4*)(Ab + ra * 128 + (((kq * 2 + 1) ^ s) * 16));
            short8 v;
            v[0] = (short)f2bf(lo[0]); v[1] = (short)f2bf(lo[1]);
            v[2] = (short)f2bf(lo[2]); v[3] = (short)f2bf(lo[3]);
            v[4] = (short)f2bf(hi[0]); v[5] = (short)f2bf(hi[1]);
            v[6] = (short)f2bf(hi[2]); v[7] = (short)f2bf(hi[3]);
            af[i] = v;
        }
#pragma unroll
        for (int j = 0; j < 2; ++j) {
            const int nb = j * 16 + lr;
            bfr[j] = *(const short8*)(Bb + nb * 64 + ((kq ^ ((nb >> 1) & 3)) * 16));
        }
#pragma unroll
        for (int i = 0; i < 4; ++i)
#pragma unroll
            for (int j = 0; j < 2; ++j)
                acc[i][j] = __builtin_amdgcn_mfma_f32_16x16x32_bf16(af[i], bfr[j], acc[i][j], 0, 0, 0);
    };

    // prologue
    ISSUE(0);
    ISSUE(1);
    asm volatile("s_waitcnt vmcnt(9)" ::: "memory");   // step-0 group landed
    WRITEB(0);
    asm volatile("s_waitcnt lgkmcnt(0)" ::: "memory");
    __builtin_amdgcn_s_barrier();

#pragma unroll
    for (int st = 0; st < 32; ++st) {
        COMPUTE(st);                                   // readers: A[st%3], B[st&1]
        if (st < 30) {
            ISSUE(st + 2);                             // writers: A[(st+2)%3], breg[st&1]
            asm volatile("s_waitcnt vmcnt(9)" ::: "memory");   // st+1 landed; st+2 in flight
            WRITEB(st + 1);                            // writer: B[(st+1)&1]
            asm volatile("s_waitcnt lgkmcnt(0)" ::: "memory");
            __builtin_amdgcn_s_barrier();
        } else if (st == 30) {
            asm volatile("s_waitcnt vmcnt(0)" ::: "memory");   // drain step-31 group
            WRITEB(31);
            asm volatile("s_waitcnt lgkmcnt(0)" ::: "memory");
            __builtin_amdgcn_s_barrier();
        }
    }

    // ---------------- fused BN + Swish epilogue ----------------
    float s1[2] = {0.f, 0.f}, s2[2] = {0.f, 0.f};
#pragma unroll
    for (int i = 0; i < 4; ++i)
#pragma unroll
        for (int j = 0; j < 2; ++j)
#pragma unroll
            for (int r = 0; r < 4; ++r) {
                const float v = acc[i][j][r];
                s1[j] += v; s2[j] += v * v;
            }
#pragma unroll
    for (int j = 0; j < 2; ++j) {          // reduce across kq groups (lanes sharing lr)
        s1[j] += __shfl_xor(s1[j], 16); s2[j] += __shfl_xor(s2[j], 16);
        s1[j] += __shfl_xor(s1[j], 32); s2[j] += __shfl_xor(s2[j], 32);
    }
    if (kq == 0) {
#pragma unroll
        for (int j = 0; j < 2; ++j) {
            wps1[wave][j * 16 + lr] = s1[j];
            wps2[wave][j * 16 + lr] = s2[j];
        }
    }
    __syncthreads();
    if (t < 32) {
        float a1 = wps1[0][t] + wps1[1][t] + wps1[2][t] + wps1[3][t];
        float a2 = wps2[0][t] + wps2[1][t] + wps2[2][t] + wps2[3][t];
        const float mean = a1 * (1.0f / 256.0f);
        const float var  = a2 * (1.0f / 256.0f) - mean * mean;   // biased (jnp.var)
        const float istd = rsqrtf(var + 1e-5f);
        const float ga = gamma[gcol0 + t];
        sa[t] = ga * istd;
        sb[t] = beta[gcol0 + t] - mean * ga * istd;
    }
    __syncthreads();

    // apply affine + swish; C/D layout col=lane&15, row=(lane>>4)*4+reg
#pragma unroll
    for (int i = 0; i < 4; ++i) {
        const int row0 = wave * 64 + i * 16 + kq * 4;
#pragma unroll
        for (int j = 0; j < 2; ++j) {
            const int col = j * 16 + lr;
            const float a = sa[col], b2 = sb[col];
#pragma unroll
            for (int r = 0; r < 4; ++r) {
                const float z = a * acc[i][j][r] + b2;
                out[(size_t)(row0 + r) * 8192 + gcol0 + col] = z / (1.0f + expf(-z));
            }
        }
    }
}

extern "C" void kernel_launch(void* const* d_in, const int* in_sizes, int n_in,
                              void* d_out, int out_size, void* d_ws, size_t ws_size,
                              hipStream_t stream) {
    const float* x     = (const float*)d_in[0];
    const float* W     = (const float*)d_in[1];
    // d_in[2] = bias: cancelled exactly by BN mean subtraction -> unused
    const float* gamma = (const float*)d_in[3];
    const float* beta  = (const float*)d_in[4];
    // d_in[5] = mask: implicit in block structure -> unused
    float* out = (float*)d_out;

    fused_kernel<<<256, 256, 0, stream>>>(x, W, gamma, beta, out);
}

// Round 10
// 25.599 us; speedup vs baseline: 1.3685x; 1.3685x over previous
//
#include <hip/hip_runtime.h>
#include <hip/hip_bf16.h>

// DecoderBlock: block-sparse masked linear (8 GEMMs M=256,N=1024,K=1024)
// + BatchNorm1d (batch stats; bias cancels exactly) + Swish.
// FUSED: block = full batch (256 rows) x 32 features -> BN stats block-local.
// grid 256 = 8 g x 32 nt; g = bid&7 -> XCD-local x slice (512KB bf16 in L2).
// Round-10: de-gate the barrier chain from W's HBM latency.
//   per iter: ISSUE_A(st+2) [8 GLL]; ISSUE_W(st+3) [2 loads, reg ring 4];
//             WRITEB(st+1) [compiler waits W(st+1), 3-iter lead];
//             vmcnt(12)  -> gates ONLY A(st+1) (L2, 1-iter lead);
//             lgkmcnt(0); s_barrier.
//   W retirement is never in the barrier chain (in-order vmcnt: W always newer).

typedef float  f32x4  __attribute__((ext_vector_type(4)));
typedef short  short8 __attribute__((ext_vector_type(8)));
typedef unsigned short u16x8 __attribute__((ext_vector_type(8)));

static __device__ __forceinline__ unsigned short f2bf(float f) {
    unsigned int u = __float_as_uint(f);
    u += 0x7FFFu + ((u >> 16) & 1u);          // RNE (inputs finite)
    return (unsigned short)(u >> 16);
}

#define GLL(gp, lp) __builtin_amdgcn_global_load_lds( \
    (const __attribute__((address_space(1))) unsigned int*)(gp), \
    (__attribute__((address_space(3))) unsigned int*)(lp), 16, 0, 0)

// ---------------- x f32 -> bf16 (12 MB traffic; result L2/L3-resident) ----------------
__global__ __launch_bounds__(256) void conv_kernel(const float* __restrict__ x,
                                                   unsigned short* __restrict__ xb) {
    const int base = blockIdx.x * 1024 + threadIdx.x;
#pragma unroll
    for (int i = 0; i < 4; ++i) {
        const int cid = base + i * 256;               // 8-float chunk id
        const f32x4 a = *(const f32x4*)(x + (size_t)cid * 8);
        const f32x4 b = *(const f32x4*)(x + (size_t)cid * 8 + 4);
        u16x8 v;
        v[0] = f2bf(a[0]); v[1] = f2bf(a[1]); v[2] = f2bf(a[2]); v[3] = f2bf(a[3]);
        v[4] = f2bf(b[0]); v[5] = f2bf(b[1]); v[6] = f2bf(b[2]); v[7] = f2bf(b[3]);
        *(u16x8*)(xb + (size_t)cid * 8) = v;
    }
}

// ---------------- fused GEMM + BN + Swish ----------------
// Block: M=256 x N=32, K=1024, BK=64 (16 steps). 4 waves stacked in M.
// A: [256][64] bf16 LDS x3 (GLL, source pre-swizzle c^=r&7), issued 2 ahead.
// B: [32][64] bf16 LDS x2; W f32 reg-ring depth 4, issued 3 ahead.
__global__ __launch_bounds__(256, 1) void fused_kernel(
    const unsigned short* __restrict__ xb, const float* __restrict__ W,
    const float* __restrict__ gamma, const float* __restrict__ beta,
    float* __restrict__ out)
{
    __shared__ __align__(16) char ldsA[3][32768];
    __shared__ __align__(16) char ldsB[2][4096];
    __shared__ float wps1[4][32], wps2[4][32];
    __shared__ float sa[32], sb[32];

    const int bid = blockIdx.x;
    const int g   = bid & 7;               // channel group -> XCD (round-robin)
    const int nt  = bid >> 3;              // 0..31
    const int o   = g * 4 + (nt >> 3);
    const int f0  = (nt & 7) * 32;
    const int gcol0 = o * 256 + f0;

    const int t    = threadIdx.x;
    const int wave = t >> 6;
    const int lane = t & 63;
    const int lr   = lane & 15;
    const int kq   = lane >> 4;

    f32x4 acc[4][2];
    const f32x4 zero = {0.f, 0.f, 0.f, 0.f};
#pragma unroll
    for (int i = 0; i < 4; ++i) { acc[i][0] = zero; acc[i][1] = zero; }

    f32x4 breg[4][2];                      // W prefetch ring, depth 4

    auto ISSUE_A = [&](int st) {           // 8 GLL (16B), source pre-swizzled
        const unsigned short* asrc = xb + g * 1024 + st * 64;
        char* Ab = ldsA[st % 3];
#pragma unroll
        for (int i = 0; i < 8; ++i) {
            const int cid = i * 256 + t;
            const int r = cid >> 3, c = cid & 7;
            GLL(asrc + (size_t)r * 8192 + (c ^ (r & 7)) * 8, Ab + cid * 16);
        }
    };
    auto ISSUE_W = [&](int st) {           // 2 x 16B loads into ring slot st&3
        const int cp = st >> 2, kc = (st & 3) * 64;
        const float* bsrc = W + ((size_t)((o * 32 + g * 4 + cp) * 256 + f0)) * 256 + kc
                              + (size_t)(t >> 3) * 256 + (t & 7) * 8;
        breg[st & 3][0] = *(const f32x4*)bsrc;
        breg[st & 3][1] = *(const f32x4*)(bsrc + 4);
    };
    auto WRITEB = [&](int st) {            // cvt + swizzled ds_write (W(st) has 3-iter lead)
        const int n = t >> 3, c = t & 7;
        short8 v;
        v[0] = (short)f2bf(breg[st & 3][0][0]); v[1] = (short)f2bf(breg[st & 3][0][1]);
        v[2] = (short)f2bf(breg[st & 3][0][2]); v[3] = (short)f2bf(breg[st & 3][0][3]);
        v[4] = (short)f2bf(breg[st & 3][1][0]); v[5] = (short)f2bf(breg[st & 3][1][1]);
        v[6] = (short)f2bf(breg[st & 3][1][2]); v[7] = (short)f2bf(breg[st & 3][1][3]);
        *(short8*)(ldsB[st & 1] + n * 128 + ((c ^ (n & 7)) * 16)) = v;
    };
    auto COMPUTE = [&](int st) {
        const char* Ab = ldsA[st % 3];
        const char* Bb = ldsB[st & 1];
#pragma unroll
        for (int ks = 0; ks < 2; ++ks) {
            short8 af[4], bfr[2];
#pragma unroll
            for (int i = 0; i < 4; ++i) {
                const int ra = wave * 64 + i * 16 + lr;
                af[i] = *(const short8*)(Ab + ra * 128 + (((ks * 4 + kq) ^ (ra & 7)) * 16));
            }
#pragma unroll
            for (int j = 0; j < 2; ++j) {
                const int n = j * 16 + lr;
                bfr[j] = *(const short8*)(Bb + n * 128 + (((ks * 4 + kq) ^ (n & 7)) * 16));
            }
#pragma unroll
            for (int i = 0; i < 4; ++i)
#pragma unroll
                for (int j = 0; j < 2; ++j)
                    acc[i][j] = __builtin_amdgcn_mfma_f32_16x16x32_bf16(af[i], bfr[j], acc[i][j], 0, 0, 0);
        }
    };

    // prologue: A(0),A(1) then W(0..2); WRITEB(0)'s compiler wait on W(0)
    // (in-order) also retires A(0),A(1). W(1),W(2) stay in flight.
    ISSUE_A(0);
    ISSUE_A(1);
    ISSUE_W(0);
    ISSUE_W(1);
    ISSUE_W(2);
    WRITEB(0);
    asm volatile("s_waitcnt lgkmcnt(0)" ::: "memory");
    __builtin_amdgcn_s_barrier();

#pragma unroll
    for (int st = 0; st < 16; ++st) {
        COMPUTE(st);                                   // reads A[st%3], B[st&1]
        if (st <= 13) ISSUE_A(st + 2);                 // writes A[(st+2)%3]
        if (st <= 12) ISSUE_W(st + 3);                 // newest vm ops: W
        if (st <= 14) {
            WRITEB(st + 1);                            // waits W(st+1) only (3-iter lead)
            if (st <= 12) {
                // outstanding allowed: W(st+2)2 + A(st+2)8 + W(st+3)2 -> gates A(st+1)
                asm volatile("s_waitcnt vmcnt(12)" ::: "memory");
            } else if (st == 13) {
                asm volatile("s_waitcnt vmcnt(8)" ::: "memory");   // allow A(15); gate A(14),W(15)
            } else {
                asm volatile("s_waitcnt vmcnt(0)" ::: "memory");   // drain A(15)
            }
            asm volatile("s_waitcnt lgkmcnt(0)" ::: "memory");
            __builtin_amdgcn_s_barrier();
        }
    }

    // ---------------- fused BN + Swish epilogue ----------------
    float s1[2] = {0.f, 0.f}, s2[2] = {0.f, 0.f};
#pragma unroll
    for (int i = 0; i < 4; ++i)
#pragma unroll
        for (int j = 0; j < 2; ++j)
#pragma unroll
            for (int r = 0; r < 4; ++r) {
                const float v = acc[i][j][r];
                s1[j] += v; s2[j] += v * v;
            }
#pragma unroll
    for (int j = 0; j < 2; ++j) {          // reduce across kq groups (lanes sharing lr)
        s1[j] += __shfl_xor(s1[j], 16); s2[j] += __shfl_xor(s2[j], 16);
        s1[j] += __shfl_xor(s1[j], 32); s2[j] += __shfl_xor(s2[j], 32);
    }
    if (kq == 0) {
#pragma unroll
        for (int j = 0; j < 2; ++j) {
            wps1[wave][j * 16 + lr] = s1[j];
            wps2[wave][j * 16 + lr] = s2[j];
        }
    }
    __syncthreads();
    if (t < 32) {
        float a1 = wps1[0][t] + wps1[1][t] + wps1[2][t] + wps1[3][t];
        float a2 = wps2[0][t] + wps2[1][t] + wps2[2][t] + wps2[3][t];
        const float mean = a1 * (1.0f / 256.0f);
        const float var  = a2 * (1.0f / 256.0f) - mean * mean;   // biased (jnp.var)
        const float istd = rsqrtf(var + 1e-5f);
        const float ga = gamma[gcol0 + t];
        sa[t] = ga * istd;
        sb[t] = beta[gcol0 + t] - mean * ga * istd;
    }
    __syncthreads();

    // apply affine + swish; C/D layout col=lane&15, row=(lane>>4)*4+reg
#pragma unroll
    for (int i = 0; i < 4; ++i) {
        const int row0 = wave * 64 + i * 16 + kq * 4;
#pragma unroll
        for (int j = 0; j < 2; ++j) {
            const int col = j * 16 + lr;
            const float a = sa[col], b2 = sb[col];
#pragma unroll
            for (int r = 0; r < 4; ++r) {
                const float z = a * acc[i][j][r] + b2;
                out[(size_t)(row0 + r) * 8192 + gcol0 + col] = z / (1.0f + expf(-z));
            }
        }
    }
}

extern "C" void kernel_launch(void* const* d_in, const int* in_sizes, int n_in,
                              void* d_out, int out_size, void* d_ws, size_t ws_size,
                              hipStream_t stream) {
    const float* x     = (const float*)d_in[0];
    const float* W     = (const float*)d_in[1];
    // d_in[2] = bias: cancelled exactly by BN mean subtraction -> unused
    const float* gamma = (const float*)d_in[3];
    const float* beta  = (const float*)d_in[4];
    // d_in[5] = mask: implicit in block structure -> unused
    float* out = (float*)d_out;

    unsigned short* xb = (unsigned short*)d_ws;   // 4MB bf16 x

    conv_kernel<<<256, 256, 0, stream>>>(x, xb);
    fused_kernel<<<256, 256, 0, stream>>>(xb, W, gamma, beta, out);
}